// Round 12
// baseline (111.447 us; speedup 1.0000x reference)
//
#include <hip/hip_runtime.h>
#include <hip/hip_bf16.h>

// KAN harmonic-basis GEMM, v15: int8 MFMA (16x16x64) — halves B bytes (DMA,
// LDS reads) AND matrix instruction count vs bf16, using the 4.7x absmax
// headroom (0.25 vs 1.165) for quantization.
// out[b,h] = sum_{d,f} basis(x[b,d])[f] * W[d,f,h] + sum_d b[d,h]
//
// f=0 + bias -> fp32 partials c_part[8][256] (exact), summed in epilogue.
// f=1..10    -> i8 MFMA GEMM: A = rint(127*sin/cos(kx)) (|.|<=127),
//              B = clamp(rint(W*127/1.6)) (W ~ N(0,0.30), col absmax ~1.45),
//              out = D_i32 * (1.6/127^2) + exact f0/bias part.
//              Per-term abs err ~0.005, sqrt(2560)-walk -> absmax ~0.3-0.7.
//
// v15 (v14 ledger: wall 40us ~= DMA 9 + VALU 15 + LDS 13 + MFMA 8; all
// bf16-floored. i8: DMA 4.5, LDS 6.5, MFMA ~4, VALU ~same):
//   - K-packing: one 16x16x64 MFMA covers a full harmonic PAIR (sin k, cos k)
//     over 32 d. Hardware k-slot e (lane koff, byte e): half = e>>3 (0=sin f,
//     1=cos f), dd = e&7, d = dtile*32 + koff*8 + dd. A-pack and Wfrag agree
//     on this order; A/B symmetric lane maps (verified for bf16 here) make
//     the contraction order-independent.
//   - Skeleton = v14 verified: BM=128 x BN=128, grid 128x2, 8 waves
//     (wr4 x wc2), 5-slot ring, stage-ahead-3, counted vmcnt, one barrier
//     per phase. Phase = 1 ktp (harmonic pair) = 8KB/block staged, 1
//     global_load_lds per wave per phase.
//   - vmcnt audit (1 load/stage; x4 at q==2): q0:3 (retires x4+S_n), q1:3,
//     q2:7, q3:7, q4:7. Prologue: x4 then S0,S1,S2.
//   - LDS 12 x 8KB = 96KB (slots 0..4 used; pad forces 1 block/CU).

#define BDIM 16384
#define DDIM 256
#define HOUT 256
#define BM 128
#define BN 128
#define NKTP 40

typedef int intx4 __attribute__((ext_vector_type(4)));
typedef float floatx4 __attribute__((ext_vector_type(4)));

#define BSCALE 79.375f          // 127/1.6
#define QSCALE (1.6f / 16129.f) // 1.6/127^2

__device__ __forceinline__ int pk4i8(float a, float b, float c, float d) {
    // inputs pre-scaled to [-127,127]
    const int q0 = (int)rintf(a);
    const int q1 = (int)rintf(b);
    const int q2 = (int)rintf(c);
    const int q3 = (int)rintf(d);
    return (q0 & 255) | ((q1 & 255) << 8) | ((q2 & 255) << 16) | (q3 << 24);
}

// grid 168 x 256 threads.
// blocks [0,160): ktp = bid>>2, cg = (bid&3)*4 + (t>>6), lane = t&63.
//   Wfrag8[chunk = ktp*16+cg][lane][16B]: byte e: half=e>>3, dd=e&7,
//   d = (ktp/5)*32 + (lane>>4)*8 + dd, f = 2*(ktp%5+1)-1+half,
//   col = cg*16 + (lane&15); value = clamp(rint(W[d][f][col]*127/1.6)).
// blocks [160,168): p = bid-160; c_part[p][h] = sum_{d in p*32..+32} W[d][0][h]+b[d][h]
__global__ void prep_kernel(const float* __restrict__ W, const float* __restrict__ bias,
                            signed char* __restrict__ Wfrag8, float* __restrict__ c_part) {
    const int bid = blockIdx.x;
    const int t = threadIdx.x;
    if (bid < 4 * NKTP) {
        const int ktp = bid >> 2;
        const int cg = (bid & 3) * 4 + (t >> 6);
        const int lane = t & 63;
        const int l15 = lane & 15;
        const int koff = lane >> 4;
        const int kh = ktp % 5 + 1;          // harmonic 1..5
        const int dtile = ktp / 5;
        const int col = cg * 16 + l15;
        union { signed char c[16]; int4 v; } u;
#pragma unroll
        for (int e = 0; e < 16; ++e) {
            const int half = e >> 3;
            const int dd = e & 7;
            const int d = dtile * 32 + koff * 8 + dd;
            const int f = 2 * kh - 1 + half;
            const float w = W[((size_t)d * 11 + f) * 256 + col];
            const float wq = fminf(fmaxf(w * BSCALE, -127.f), 127.f);
            u.c[e] = (signed char)(int)rintf(wq);
        }
        *(int4*)(Wfrag8 + ((size_t)(ktp * 16 + cg) * 64 + lane) * 16) = u.v;
    } else {
        const int p = bid - 4 * NKTP;
        float acc = 0.f;
#pragma unroll
        for (int dd = 0; dd < 32; ++dd) {
            const int d = p * 32 + dd;
            acc += W[(size_t)(d * 11) * 256 + t] + bias[(size_t)d * 256 + t];
        }
        c_part[p * 256 + t] = acc;
    }
}

__global__ __launch_bounds__(512, 2)
void kan_gemm(const float* __restrict__ x, const signed char* __restrict__ Wfrag8,
              const float* __restrict__ c_part, float* __restrict__ out) {
    // 5-slot ring of 8KB phases; padded to 96KB -> 1 block/CU.
    __shared__ int4 BsV[12 * 512];
    char* Bs = (char*)BsV;

    const int t = threadIdx.x;
    const int m0 = blockIdx.x * BM;
    const int h0 = blockIdx.y * BN;

    const int lane = t & 63;
    const int wave = t >> 6;         // 0..7
    const int wr = wave >> 1;        // row quarter (32 rows)
    const int wc = wave & 1;         // col half (64 cols)
    const int l15 = lane & 15;
    const int koff = lane >> 4;

    intx4 acc[2][4];
#pragma unroll
    for (int i = 0; i < 2; ++i)
#pragma unroll
        for (int j = 0; j < 4; ++j)
            acc[i][j] = (intx4){0, 0, 0, 0};

    // lane's x rows: i=0 -> m0 + wr*32 + l15, i=1 -> +16; d-slots koff*8..+8
    const float* xr0 = x + (size_t)(m0 + wr * 32 + l15) * DDIM + koff * 8;

    // this wave's staged chunk: colgroup cg = h0/16 + wave; per-lane source
    // slot lane*16 (prep stored lane-ordered); LDS dst is wave-uniform.
    const signed char* gbase = Wfrag8 + ((size_t)(h0 >> 4) + wave) * 1024 + lane * 16;

    // ---- prologue: x (4 loads) FIRST, then stages S0,S1,S2 (3 loads) ----
    float4 xn[4];
    xn[0] = *(const float4*)(xr0 + 0);
    xn[1] = *(const float4*)(xr0 + 4);
    xn[2] = *(const float4*)(xr0 + 16 * DDIM + 0);
    xn[3] = *(const float4*)(xr0 + 16 * DDIM + 4);

#pragma unroll
    for (int p = 0; p < 3; ++p)
        __builtin_amdgcn_global_load_lds((const void*)(gbase + (size_t)p * 16384),
                                         (void*)(Bs + p * 8192 + wave * 1024), 16, 0, 0);

    // Chebyshev state (f32, proven numerics)
    float sc[16], cc[16], sp[16], cp[16], t2c[16];

#pragma unroll 1
    for (int dt = 0; dt < 8; ++dt) {
#pragma unroll
        for (int q = 0; q < 5; ++q) {
            // phase p = dt*5 + q; compute slot = q; write slot = (q+3)%5.

            // x prefetch for next dtile at q==2 (before stage issue).
            if (q == 2) {
                const int dn = (dt < 7) ? dt + 1 : 7;
                xn[0] = *(const float4*)(xr0 + dn * 32 + 0);
                xn[1] = *(const float4*)(xr0 + dn * 32 + 4);
                xn[2] = *(const float4*)(xr0 + 16 * DDIM + dn * 32 + 0);
                xn[3] = *(const float4*)(xr0 + 16 * DDIM + dn * 32 + 4);
            }

            // ---- issue stage(p+3) into slot (q+3)%5 (clamped tail) ----
            {
                int pt = dt * 5 + q + 3;
                if (pt > 39) pt = 39;
                __builtin_amdgcn_global_load_lds(
                    (const void*)(gbase + (size_t)pt * 16384),
                    (void*)(Bs + ((q + 3) % 5) * 8192 + wave * 1024), 16, 0, 0);
            }

            // ---- counted wait (audited: q0..q4 = 3,3,7,7,7) + barrier ----
            __builtin_amdgcn_sched_barrier(0);
            if (q >= 2) {
                asm volatile("s_waitcnt vmcnt(7)" ::: "memory");
            } else {
                asm volatile("s_waitcnt vmcnt(3)" ::: "memory");
            }
            __builtin_amdgcn_s_barrier();
            __builtin_amdgcn_sched_barrier(0);

            if (q == 0) {
                // ---- dtile start: sincos of 16 elems; Chebyshev init ----
                const float xv[16] = {xn[0].x, xn[0].y, xn[0].z, xn[0].w,
                                      xn[1].x, xn[1].y, xn[1].z, xn[1].w,
                                      xn[2].x, xn[2].y, xn[2].z, xn[2].w,
                                      xn[3].x, xn[3].y, xn[3].z, xn[3].w};
#pragma unroll
                for (int g = 0; g < 16; ++g) {
                    __sincosf(xv[g], &sc[g], &cc[g]);
                    t2c[g] = cc[g] + cc[g];
                    sp[g] = 0.f;
                    cp[g] = 1.f;
                }
            }

            // ---- pack A (i8): bytes e: 0..7 = sin d0..7, 8..15 = cos d0..7 ----
            intx4 a0, a1;
            a0[0] = pk4i8(sc[0] * 127.f, sc[1] * 127.f, sc[2] * 127.f, sc[3] * 127.f);
            a0[1] = pk4i8(sc[4] * 127.f, sc[5] * 127.f, sc[6] * 127.f, sc[7] * 127.f);
            a0[2] = pk4i8(cc[0] * 127.f, cc[1] * 127.f, cc[2] * 127.f, cc[3] * 127.f);
            a0[3] = pk4i8(cc[4] * 127.f, cc[5] * 127.f, cc[6] * 127.f, cc[7] * 127.f);
            a1[0] = pk4i8(sc[8] * 127.f, sc[9] * 127.f, sc[10] * 127.f, sc[11] * 127.f);
            a1[1] = pk4i8(sc[12] * 127.f, sc[13] * 127.f, sc[14] * 127.f, sc[15] * 127.f);
            a1[2] = pk4i8(cc[8] * 127.f, cc[9] * 127.f, cc[10] * 127.f, cc[11] * 127.f);
            a1[3] = pk4i8(cc[12] * 127.f, cc[13] * 127.f, cc[14] * 127.f, cc[15] * 127.f);

            // ---- B frags (this wc's 4 colgroups) + 8 MFMA (K=64 = sin+cos) ----
            const char* fb = Bs + q * 8192 + (wc * 4) * 1024 + lane * 16;
            const intx4 b0 = *(const intx4*)(fb);
            const intx4 b1 = *(const intx4*)(fb + 1024);
            const intx4 b2 = *(const intx4*)(fb + 2048);
            const intx4 b3 = *(const intx4*)(fb + 3072);

            acc[0][0] = __builtin_amdgcn_mfma_i32_16x16x64_i8(a0, b0, acc[0][0], 0, 0, 0);
            acc[1][0] = __builtin_amdgcn_mfma_i32_16x16x64_i8(a1, b0, acc[1][0], 0, 0, 0);
            acc[0][1] = __builtin_amdgcn_mfma_i32_16x16x64_i8(a0, b1, acc[0][1], 0, 0, 0);
            acc[1][1] = __builtin_amdgcn_mfma_i32_16x16x64_i8(a1, b1, acc[1][1], 0, 0, 0);
            acc[0][2] = __builtin_amdgcn_mfma_i32_16x16x64_i8(a0, b2, acc[0][2], 0, 0, 0);
            acc[1][2] = __builtin_amdgcn_mfma_i32_16x16x64_i8(a1, b2, acc[1][2], 0, 0, 0);
            acc[0][3] = __builtin_amdgcn_mfma_i32_16x16x64_i8(a0, b3, acc[0][3], 0, 0, 0);
            acc[1][3] = __builtin_amdgcn_mfma_i32_16x16x64_i8(a1, b3, acc[1][3], 0, 0, 0);

            // advance harmonic k -> k+1 (except after k=5)
            if (q < 4) {
#pragma unroll
                for (int g = 0; g < 16; ++g) {
                    const float ns = t2c[g] * sc[g] - sp[g];
                    const float nc = t2c[g] * cc[g] - cp[g];
                    sp[g] = sc[g]; cp[g] = cc[g];
                    sc[g] = ns;   cc[g] = nc;
                }
            }
        }
    }

    // drain redundant tail DMAs
    asm volatile("s_waitcnt vmcnt(0)" ::: "memory");

    // ---- epilogue: C/D layout col=lane&15, row=(lane>>4)*4+reg ----
    float cj[4];
#pragma unroll
    for (int j = 0; j < 4; ++j) {
        const int col = h0 + wc * 64 + j * 16 + l15;
        float s = 0.f;
#pragma unroll
        for (int q = 0; q < 8; ++q) s += c_part[q * 256 + col];
        cj[j] = s;
    }
#pragma unroll
    for (int i = 0; i < 2; ++i) {
        const int row0 = m0 + wr * 32 + i * 16 + koff * 4;
#pragma unroll
        for (int j = 0; j < 4; ++j) {
            const int col = h0 + wc * 64 + j * 16 + l15;
#pragma unroll
            for (int r = 0; r < 4; ++r)
                out[(size_t)(row0 + r) * HOUT + col] =
                    (float)acc[i][j][r] * QSCALE + cj[j];
        }
    }
}

extern "C" void kernel_launch(void* const* d_in, const int* in_sizes, int n_in,
                              void* d_out, int out_size, void* d_ws, size_t ws_size,
                              hipStream_t stream) {
    const float* x = (const float*)d_in[0];
    const float* W = (const float*)d_in[1];
    const float* b = (const float*)d_in[2];
    float* out = (float*)d_out;

    signed char* Wfrag8 = (signed char*)d_ws;                 // 655,360 B
    float* c_part = (float*)((char*)d_ws + 655360);           // 8 KB

    prep_kernel<<<4 * NKTP + 8, 256, 0, stream>>>(W, b, Wfrag8, c_part);
    kan_gemm<<<dim3(BDIM / BM, HOUT / BN), 512, 0, stream>>>(x, Wfrag8, c_part, out);
}

// Round 13
// 97.242 us; speedup vs baseline: 1.1461x; 1.1461x over previous
//
#include <hip/hip_runtime.h>
#include <hip/hip_bf16.h>
#include <hip/hip_fp16.h>

// KAN harmonic-basis GEMM, v16: v14 skeleton + hw v_sin/v_cos + f16-resident
// A state feeding f16 MFMA directly (zero pack).
// out[b,h] = sum_{d,f} basis(x[b,d])[f] * W[d,f,h] + sum_d b[d,h]
//
// f=0 + bias -> fp32 partials c_part[8][256], summed in GEMM epilogue.
// f=1..10    -> f16 MFMA GEMM, M=16384, N=256, K=2560.
//
// v16 (v15 post-mortem: i8 pack cost +10us VALU > its 10us mem savings.
// v14 audit: sincos ~3200 ops/wave (libm range reduction) + cheby 2048 +
// pack 640 dominate VALU, the largest ledger term):
//   - hw transcendentals: x ~ N(0,1) -> |x/2pi| < 1 rev, inside v_sin/v_cos
//     valid range. 3 ops/elem vs ~25 for __sincosf.
//   - A state lives as __half2 (v11-proven recurrence numerics) and is the
//     MFMA A operand DIRECTLY (mfma_f32_16x16x32_f16, same layout family as
//     bf16: dword p = elems {2p,2p+1} = k-slots dd 2p,2p+1). Pack stage
//     eliminated; angle-addition advance in packed fp16 (4 ops / 2 elems).
//   - B stored f16 by prep (|W|<~1.6; 11-bit mantissa beats bf16).
//   - Memory skeleton = v14 verified: BM=128 x BN=128, grid 128x2 = 256
//     blocks = 1 block/CU (96KB pad), 8 waves (wr4 x wc2), 5-slot ring of
//     16KB phases, stage-ahead-3 via global_load_lds (2 loads/wave/phase),
//     counted vmcnt 6/6/10/10/6, one s_barrier per phase.

#define BDIM 16384
#define DDIM 256
#define HOUT 256
#define NKT  80
#define BM 128
#define BN 128

typedef _Float16 halfx8 __attribute__((ext_vector_type(8)));
typedef float floatx4 __attribute__((ext_vector_type(4)));

__device__ __forceinline__ unsigned short f2h(float f) {
    union { _Float16 h; unsigned short u; } v;
    v.h = (_Float16)f;
    return v.u;
}

#define INV2PI 0.15915494309189535f

__device__ __forceinline__ void hwsincos(float x, float* s, float* c) {
    const float r = x * INV2PI;      // revolutions; |r| < 1 for N(0,1) inputs
    float sv, cv;
    asm("v_sin_f32 %0, %1" : "=v"(sv) : "v"(r));
    asm("v_cos_f32 %0, %1" : "=v"(cv) : "v"(r));
    *s = sv; *c = cv;
}

// grid 328 x 256 threads.
// blocks [0,320): kt = bid>>2, sub = bid&3:
//   Wfrag[kt][n=t][dd = sub*8 .. +8] = f16(W[dtile*32+dd][kt%10+1][n])
// blocks [320,328): p = bid-320; c_part[p][h] = sum_{d in p*32..+32} W[d][0][h]+b[d][h]
__global__ void prep_kernel(const float* __restrict__ W, const float* __restrict__ bias,
                            unsigned short* __restrict__ Wfrag, float* __restrict__ c_part) {
    const int bid = blockIdx.x;
    const int t = threadIdx.x;
    if (bid < 4 * NKT) {
        const int kt = bid >> 2;
        const int sub = bid & 3;
        const int dtile = kt / 10;
        const int f = kt - dtile * 10 + 1;
        const int d0 = dtile * 32 + sub * 8;
        const float* wsrc = W + ((size_t)d0 * 11 + f) * 256 + t;
        union { unsigned short s[8]; int4 v; } buf;
#pragma unroll
        for (int dd = 0; dd < 8; ++dd)
            buf.s[dd] = f2h(wsrc[(size_t)dd * 11 * 256]);
        *(int4*)(Wfrag + ((size_t)kt * 256 + t) * 32 + sub * 8) = buf.v;
    } else {
        const int p = bid - 4 * NKT;
        float acc = 0.f;
#pragma unroll
        for (int dd = 0; dd < 32; ++dd) {
            const int d = p * 32 + dd;
            acc += W[(size_t)(d * 11) * 256 + t] + bias[(size_t)d * 256 + t];
        }
        c_part[p * 256 + t] = acc;
    }
}

__global__ __launch_bounds__(512, 2)
void kan_gemm(const float* __restrict__ x, const unsigned short* __restrict__ Wfrag,
              const float* __restrict__ c_part, float* __restrict__ out) {
    // 5-slot ring of 16KB phases; 6th slot = pad to 96KB -> 1 block/CU forced.
    __shared__ unsigned short Bs[6][2 * 8 * 512];

    const int t = threadIdx.x;
    const int m0 = blockIdx.x * BM;
    const int h0 = blockIdx.y * BN;

    const int lane = t & 63;
    const int wave = t >> 6;         // 0..7
    const int wr = wave >> 1;        // row quarter (32 rows)
    const int wc = wave & 1;         // col half (64 cols)
    const int l15 = lane & 15;
    const int koff = lane >> 4;

    floatx4 acc[2][4];
#pragma unroll
    for (int i = 0; i < 2; ++i)
#pragma unroll
        for (int j = 0; j < 4; ++j)
            acc[i][j] = (floatx4){0.f, 0.f, 0.f, 0.f};

    // lane's x rows: i=0 -> m0 + wr*32 + l15, i=1 -> +16; d-slots koff*8..+8
    const float* xr0 = x + (size_t)(m0 + wr * 32 + l15) * DDIM + koff * 8;

    // ---- prologue: x (4 loads) FIRST, then stages S0,S1,S2 (6 loads) ----
    float4 xn[4];
    xn[0] = *(const float4*)(xr0 + 0);
    xn[1] = *(const float4*)(xr0 + 4);
    xn[2] = *(const float4*)(xr0 + 16 * DDIM + 0);
    xn[3] = *(const float4*)(xr0 + 16 * DDIM + 4);

#pragma unroll
    for (int p = 0; p < 3; ++p) {
#pragma unroll
        for (int s = 0; s < 2; ++s) {
            const int c = wave * 2 + s;
            const int ktl = c >> 3;
            const int f = c & 7;
            const unsigned short* g = Wfrag + (size_t)(p * 2 + ktl) * 8192
                                    + (h0 + f * 16 + l15) * 32 + koff * 8;
            __builtin_amdgcn_global_load_lds((const void*)g,
                (void*)(&Bs[p][0] + c * 512), 16, 0, 0);
        }
    }

    // f16-resident harmonic state: pair p holds elems {2p,2p+1};
    // p 0..3 -> i=0 (d-slots koff*8+0..7), p 4..7 -> i=1.
    __half2 s1h[8], c1h[8], skh[8], ckh[8];

#pragma unroll 1
    for (int dt = 0; dt < 8; ++dt) {
#pragma unroll
        for (int q = 0; q < 5; ++q) {
            // phase p = dt*5 + q; compute slot = q; write slot = (q+3)%5.

            // x prefetch for next dtile at q==2 (before stage issue).
            if (q == 2) {
                const int dn = (dt < 7) ? dt + 1 : 7;
                xn[0] = *(const float4*)(xr0 + dn * 32 + 0);
                xn[1] = *(const float4*)(xr0 + dn * 32 + 4);
                xn[2] = *(const float4*)(xr0 + 16 * DDIM + dn * 32 + 0);
                xn[3] = *(const float4*)(xr0 + 16 * DDIM + dn * 32 + 4);
            }

            // ---- issue stage(p+3) into slot (q+3)%5 (clamped tail) ----
            {
                int pt = dt * 5 + q + 3;
                if (pt > 39) pt = 39;
#pragma unroll
                for (int s = 0; s < 2; ++s) {
                    const int c = wave * 2 + s;
                    const int ktl = c >> 3;
                    const int f = c & 7;
                    const unsigned short* g = Wfrag + (size_t)(pt * 2 + ktl) * 8192
                                            + (h0 + f * 16 + l15) * 32 + koff * 8;
                    __builtin_amdgcn_global_load_lds((const void*)g,
                        (void*)(&Bs[(q + 3) % 5][0] + c * 512), 16, 0, 0);
                }
            }

            // ---- counted wait (v14-audited: 6,6,10,10,6) + publish barrier ----
            __builtin_amdgcn_sched_barrier(0);
            if (q == 2 || q == 3) {
                asm volatile("s_waitcnt vmcnt(10)" ::: "memory");
            } else {
                asm volatile("s_waitcnt vmcnt(6)" ::: "memory");
            }
            __builtin_amdgcn_s_barrier();
            __builtin_amdgcn_sched_barrier(0);

            if (q == 0) {
                // ---- dtile start: hw sincos of 16 elems -> f16 state ----
                const float xv[16] = {xn[0].x, xn[0].y, xn[0].z, xn[0].w,
                                      xn[1].x, xn[1].y, xn[1].z, xn[1].w,
                                      xn[2].x, xn[2].y, xn[2].z, xn[2].w,
                                      xn[3].x, xn[3].y, xn[3].z, xn[3].w};
#pragma unroll
                for (int p = 0; p < 8; ++p) {
                    float s0, c0, s1, c1;
                    hwsincos(xv[2 * p], &s0, &c0);
                    hwsincos(xv[2 * p + 1], &s1, &c1);
                    const __half2 sh = __floats2half2_rn(s0, s1);
                    const __half2 ch = __floats2half2_rn(c0, c1);
                    s1h[p] = sh; c1h[p] = ch;
                    skh[p] = sh; ckh[p] = ch;
                }
            }

            // ---- compute 2 kt (harmonic q+1: sin then cos); A = state direct ----
#pragma unroll
            for (int s = 0; s < 2; ++s) {
                union { __half2 h2[4]; halfx8 v; } a0, a1;
                if (s == 0) {
#pragma unroll
                    for (int p = 0; p < 4; ++p) { a0.h2[p] = skh[p]; a1.h2[p] = skh[p + 4]; }
                } else {
#pragma unroll
                    for (int p = 0; p < 4; ++p) { a0.h2[p] = ckh[p]; a1.h2[p] = ckh[p + 4]; }
                }

                const unsigned short* fb = &Bs[q][(s * 8 + wc * 4) * 512 + lane * 8];
                const halfx8 b0 = *(const halfx8*)(fb);
                const halfx8 b1 = *(const halfx8*)(fb + 512);
                const halfx8 b2 = *(const halfx8*)(fb + 1024);
                const halfx8 b3 = *(const halfx8*)(fb + 1536);

                acc[0][0] = __builtin_amdgcn_mfma_f32_16x16x32_f16(a0.v, b0, acc[0][0], 0, 0, 0);
                acc[1][0] = __builtin_amdgcn_mfma_f32_16x16x32_f16(a1.v, b0, acc[1][0], 0, 0, 0);
                acc[0][1] = __builtin_amdgcn_mfma_f32_16x16x32_f16(a0.v, b1, acc[0][1], 0, 0, 0);
                acc[1][1] = __builtin_amdgcn_mfma_f32_16x16x32_f16(a1.v, b1, acc[1][1], 0, 0, 0);
                acc[0][2] = __builtin_amdgcn_mfma_f32_16x16x32_f16(a0.v, b2, acc[0][2], 0, 0, 0);
                acc[1][2] = __builtin_amdgcn_mfma_f32_16x16x32_f16(a1.v, b2, acc[1][2], 0, 0, 0);
                acc[0][3] = __builtin_amdgcn_mfma_f32_16x16x32_f16(a0.v, b3, acc[0][3], 0, 0, 0);
                acc[1][3] = __builtin_amdgcn_mfma_f32_16x16x32_f16(a1.v, b3, acc[1][3], 0, 0, 0);

                // advance harmonic k -> k+1 after the cos emit (except k=5):
                // ns = sk*c1 + ck*s1 ; nc = ck*c1 - sk*s1 (packed fp16)
                if (s == 1 && q < 4) {
#pragma unroll
                    for (int p = 0; p < 8; ++p) {
                        const __half2 t0 = __hmul2(ckh[p], s1h[p]);
                        const __half2 t1 = __hmul2(skh[p], s1h[p]);
                        const __half2 ns = __hfma2(skh[p], c1h[p], t0);
                        const __half2 nc = __hfma2(ckh[p], c1h[p], __hneg2(t1));
                        skh[p] = ns;
                        ckh[p] = nc;
                    }
                }
            }
        }
    }

    // drain redundant tail DMAs
    asm volatile("s_waitcnt vmcnt(0)" ::: "memory");

    // ---- epilogue: C/D layout col=lane&15, row=(lane>>4)*4+reg ----
    float cj[4];
#pragma unroll
    for (int j = 0; j < 4; ++j) {
        const int col = h0 + wc * 64 + j * 16 + l15;
        float s = 0.f;
#pragma unroll
        for (int q = 0; q < 8; ++q) s += c_part[q * 256 + col];
        cj[j] = s;
    }
#pragma unroll
    for (int i = 0; i < 2; ++i) {
        const int row0 = m0 + wr * 32 + i * 16 + koff * 4;
#pragma unroll
        for (int j = 0; j < 4; ++j) {
            const int col = h0 + wc * 64 + j * 16 + l15;
#pragma unroll
            for (int r = 0; r < 4; ++r)
                out[(size_t)(row0 + r) * HOUT + col] = acc[i][j][r] + cj[j];
        }
    }
}

extern "C" void kernel_launch(void* const* d_in, const int* in_sizes, int n_in,
                              void* d_out, int out_size, void* d_ws, size_t ws_size,
                              hipStream_t stream) {
    const float* x = (const float*)d_in[0];
    const float* W = (const float*)d_in[1];
    const float* b = (const float*)d_in[2];
    float* out = (float*)d_out;

    unsigned short* Wfrag = (unsigned short*)d_ws;                      // 1,310,720 B
    float* c_part = (float*)((char*)d_ws + (size_t)NKT * 256 * 32 * 2); // 8 KB

    prep_kernel<<<4 * NKT + 8, 256, 0, stream>>>(W, b, Wfrag, c_part);
    kan_gemm<<<dim3(BDIM / BM, HOUT / BN), 512, 0, stream>>>(x, Wfrag, c_part, out);
}